// Round 3
// baseline (934.350 us; speedup 1.0000x reference)
//
#include <hip/hip_runtime.h>

typedef __bf16 bf16;
typedef __bf16 bf16x8 __attribute__((ext_vector_type(8)));
typedef float f32x4 __attribute__((ext_vector_type(4)));

constexpr long NB = 16384;   // batch of triples
constexpr int  DD = 768;
constexpr int  FFD = 3072;

// ---------- helpers ----------

__device__ __forceinline__ void async16(const void* g, void* l) {
  void* gg = (void*)g;
  __builtin_amdgcn_global_load_lds((__attribute__((address_space(1))) void*)gg,
                                   (__attribute__((address_space(3))) void*)l,
                                   16, 0, 0);
}

__device__ __forceinline__ float wred(float v) {
#pragma unroll
  for (int off = 32; off; off >>= 1) v += __shfl_xor(v, off);
  return v;
}

__device__ __forceinline__ float gelu_tanh(float x) {
  float x3 = x * x * x;
  return 0.5f * x * (1.0f + tanhf(0.7978845608028654f * (x + 0.044715f * x3)));
}

// ---------- weight prep: fp32 [R][C] -> bf16 [C][R] (transpose) ----------

__global__ __launch_bounds__(256) void transpose_bf16(const float* __restrict__ src,
                                                      bf16* __restrict__ dst,
                                                      int R, int C) {
  __shared__ float t[32][33];
  int tilesC = C >> 5;
  int tc = blockIdx.x % tilesC;
  int tr = blockIdx.x / tilesC;
  int tx = threadIdx.x & 31, ty = threadIdx.x >> 5;  // ty in 0..7
#pragma unroll
  for (int i = 0; i < 4; ++i) {
    int r = tr * 32 + ty + i * 8;
    t[ty + i * 8][tx] = src[(long)r * C + tc * 32 + tx];
  }
  __syncthreads();
#pragma unroll
  for (int i = 0; i < 4; ++i) {
    int c = tc * 32 + ty + i * 8;
    dst[(long)c * R + tr * 32 + tx] = (bf16)t[tx][ty + i * 8];
  }
}

__global__ void concat_bias(const float* __restrict__ bk, const float* __restrict__ bv,
                            float* __restrict__ bkv) {
  int i = blockIdx.x * 256 + threadIdx.x;
  if (i < 2 * DD) bkv[i] = (i < DD) ? bk[i] : bv[i - DD];
}

// ---------- embedding gather + add + LN ----------
// one block per triple (chunk-local); writes chunk-local X rows and global Xc row

__global__ __launch_bounds__(256) void embed_kernel(
    long b0,
    const int* __restrict__ hid, const int* __restrict__ eid, const int* __restrict__ tid_,
    const int* __restrict__ pL,
    const float* __restrict__ tok, const float* __restrict__ rel, const float* __restrict__ ete,
    const float* __restrict__ cls, const float* __restrict__ seg, const float* __restrict__ pos,
    const float* __restrict__ g, const float* __restrict__ bln,
    bf16* __restrict__ X, bf16* __restrict__ Xc) {
  long lt = blockIdx.x;      // local triple
  long b = b0 + lt;          // global triple
  int s = threadIdx.x >> 6;  // seq position 0..3, one wave per row
  int lane = threadIdx.x & 63;
  int L = *pL;

  const float* src;
  if (s == 0) {
    src = cls;
  } else if (s == 2) {
    src = ete + (long)eid[b] * DD;
  } else {
    int id = (s == 1) ? hid[b] : tid_[b];
    int ridx = id - L;
    ridx = ridx < 0 ? 0 : (ridx > 511 ? 511 : ridx);
    src = (id < L) ? (tok + (long)id * DD) : (rel + (long)ridx * DD);
  }

  float v[12];
  float sum = 0.f, ssum = 0.f;
#pragma unroll
  for (int j = 0; j < 12; ++j) {
    int d = j * 64 + lane;
    float x = src[d] + seg[s * DD + d] + pos[s * DD + d];
    v[j] = x;
    sum += x;
    ssum += x * x;
  }
  sum = wred(sum);
  ssum = wred(ssum);
  float mean = sum * (1.0f / DD);
  float var = ssum * (1.0f / DD) - mean * mean;
  float rs = rsqrtf(var + 1e-12f);

  long row = lt * 4 + s;
#pragma unroll
  for (int j = 0; j < 12; ++j) {
    int d = j * 64 + lane;
    float y = (v[j] - mean) * rs * g[d] + bln[d];
    X[row * DD + d] = (bf16)y;
    if (s == 0) Xc[b * DD + d] = (bf16)y;
  }
}

// ---------- GEMM: C = A(bf16,row-major MxK) @ Bt(bf16, [N][K]) + bias ----------
// m97 structure: 128x128 tile, BK=32, 4 waves (2x2), 16x16x32 bf16 MFMA,
// global_load_lds width 16 staging, single-buffered LDS.
// XCD-aware bijective swizzle, auto-disabled when grid % 8 != 0.
// EPI: 0 = bf16 out, 1 = f32 out, 2 = bf16 out with gelu

template <int EPI>
__global__ __launch_bounds__(256) void gemm_bt(
    const bf16* __restrict__ A, const bf16* __restrict__ Bt,
    const float* __restrict__ bias, void* __restrict__ Cout,
    long M, long N, long K, int tilesN) {
  __shared__ __align__(16) bf16 As[128 * 32];
  __shared__ __align__(16) bf16 Bs[128 * 32];
  const int tid = threadIdx.x;
  const int w = tid >> 6;
  const int lane = tid & 63;

  long bid;
  if ((gridDim.x & 7) == 0) {
    const long cpx = gridDim.x >> 3;
    bid = (long)(blockIdx.x & 7) * cpx + (blockIdx.x >> 3);
  } else {
    bid = blockIdx.x;
  }
  const int tn = (int)(bid % tilesN);
  const long tm = bid / tilesN;
  const long m0 = tm * 128, n0 = (long)tn * 128;

  // staging addresses: wave w stages LDS chunks 2w, 2w+1 of each tile
  const int sr = lane >> 2;          // row within 16-row chunk
  const int sk = (lane & 3) * 8;     // k element offset
  const bf16* ga0 = A + (m0 + w * 32 + sr) * K + sk;
  const bf16* ga1 = ga0 + 16 * K;
  const bf16* gb0 = Bt + (n0 + w * 32 + sr) * K + sk;
  const bf16* gb1 = gb0 + 16 * K;
  bf16* la0 = As + w * 1024;
  bf16* la1 = la0 + 512;
  bf16* lb0 = Bs + w * 1024;
  bf16* lb1 = lb0 + 512;

  // fragment read coords
  const int fr = lane & 15;
  const int fk = (lane >> 4) * 8;
  const int wr = (w >> 1) * 64;
  const int wc = (w & 1) * 64;

  f32x4 acc[4][4] = {};

  const int nk = (int)(K >> 5);
  for (int kt = 0; kt < nk; ++kt) {
    const long ko = (long)kt * 32;
    async16(ga0 + ko, la0);
    async16(ga1 + ko, la1);
    async16(gb0 + ko, lb0);
    async16(gb1 + ko, lb1);
    __syncthreads();
    bf16x8 af[4], bfr[4];
#pragma unroll
    for (int m = 0; m < 4; ++m)
      af[m] = *(const bf16x8*)(As + (wr + m * 16 + fr) * 32 + fk);
#pragma unroll
    for (int n = 0; n < 4; ++n)
      bfr[n] = *(const bf16x8*)(Bs + (wc + n * 16 + fr) * 32 + fk);
#pragma unroll
    for (int m = 0; m < 4; ++m)
#pragma unroll
      for (int n = 0; n < 4; ++n)
        acc[m][n] = __builtin_amdgcn_mfma_f32_16x16x32_bf16(af[m], bfr[n], acc[m][n], 0, 0, 0);
    __syncthreads();
  }

  // epilogue: C/D layout col=lane&15, row=(lane>>4)*4+reg
  const int er = (lane >> 4) * 4;
#pragma unroll
  for (int m = 0; m < 4; ++m) {
#pragma unroll
    for (int n = 0; n < 4; ++n) {
#pragma unroll
      for (int j = 0; j < 4; ++j) {
        long row = m0 + wr + m * 16 + er + j;
        long col = n0 + wc + n * 16 + fr;
        float v = acc[m][n][j] + bias[col];
        if (EPI == 2) v = gelu_tanh(v);
        if (EPI == 1)
          ((float*)Cout)[row * N + col] = v;
        else
          ((bf16*)Cout)[row * N + col] = (bf16)v;
      }
    }
  }
}

// ---------- attention (q = cls row only), SEQ=4, per-triple ----------
// 192 threads per triple: head h = t>>4 (12 heads), 16 lanes per head, 4 dims/lane.
// Q and KV are chunk-local; ctx is global (offset b0).

__global__ __launch_bounds__(192) void attn_kernel(const bf16* __restrict__ Qch,
                                                   const bf16* __restrict__ KV,
                                                   bf16* __restrict__ ctx, long b0) {
  long lt = blockIdx.x;
  long b = b0 + lt;
  int t = threadIdx.x;
  int h = t >> 4, hl = t & 15;
  const bf16* qp = Qch + lt * DD + h * 64 + hl * 4;
  float q0 = (float)qp[0], q1 = (float)qp[1], q2 = (float)qp[2], q3 = (float)qp[3];

  const bf16* kvb = KV + lt * 4 * (2 * DD) + h * 64 + hl * 4;
  float sc[4];
#pragma unroll
  for (int i = 0; i < 4; ++i) {
    const bf16* kp = kvb + i * (2 * DD);
    float p = q0 * (float)kp[0] + q1 * (float)kp[1] + q2 * (float)kp[2] + q3 * (float)kp[3];
    p += __shfl_xor(p, 1);
    p += __shfl_xor(p, 2);
    p += __shfl_xor(p, 4);
    p += __shfl_xor(p, 8);
    sc[i] = p * 0.125f;  // / sqrt(64)
  }
  float m = fmaxf(fmaxf(sc[0], sc[1]), fmaxf(sc[2], sc[3]));
  float p0 = expf(sc[0] - m), p1 = expf(sc[1] - m), p2 = expf(sc[2] - m), p3 = expf(sc[3] - m);
  float inv = 1.0f / (p0 + p1 + p2 + p3);
  float o0 = 0.f, o1 = 0.f, o2 = 0.f, o3 = 0.f;
  float pw[4] = {p0 * inv, p1 * inv, p2 * inv, p3 * inv};
#pragma unroll
  for (int i = 0; i < 4; ++i) {
    const bf16* vp = kvb + i * (2 * DD) + DD;
    o0 += pw[i] * (float)vp[0];
    o1 += pw[i] * (float)vp[1];
    o2 += pw[i] * (float)vp[2];
    o3 += pw[i] * (float)vp[3];
  }
  bf16* op = ctx + b * DD + h * 64 + hl * 4;
  op[0] = (bf16)o0;
  op[1] = (bf16)o1;
  op[2] = (bf16)o2;
  op[3] = (bf16)o3;
}

// ---------- LN1: x1 = LN(Xc + O) (chunk-local rows) ----------

__global__ __launch_bounds__(256) void ln1_kernel(const bf16* __restrict__ Xc,
                                                  const float* __restrict__ O,
                                                  const float* __restrict__ g,
                                                  const float* __restrict__ bb,
                                                  bf16* __restrict__ x1) {
  int w = threadIdx.x >> 6, lane = threadIdx.x & 63;
  long r = (long)blockIdx.x * 4 + w;
  const bf16* xp = Xc + r * DD;
  const float* op = O + r * DD;
  float v[12], sum = 0.f, ssum = 0.f;
#pragma unroll
  for (int j = 0; j < 12; ++j) {
    int d = j * 64 + lane;
    float x = (float)xp[d] + op[d];
    v[j] = x;
    sum += x;
    ssum += x * x;
  }
  sum = wred(sum);
  ssum = wred(ssum);
  float mean = sum * (1.0f / DD);
  float var = ssum * (1.0f / DD) - mean * mean;
  float rs = rsqrtf(var + 1e-12f);
#pragma unroll
  for (int j = 0; j < 12; ++j) {
    int d = j * 64 + lane;
    x1[r * DD + d] = (bf16)((v[j] - mean) * rs * g[d] + bb[d]);
  }
}

// ---------- LN2 + score (chunk-local rows) ----------

__global__ __launch_bounds__(256) void final_kernel(const bf16* __restrict__ x1,
                                                    const float* __restrict__ F,
                                                    const float* __restrict__ g,
                                                    const float* __restrict__ bb,
                                                    const float* __restrict__ hw,
                                                    const float* __restrict__ phb,
                                                    float* __restrict__ scores) {
  int w = threadIdx.x >> 6, lane = threadIdx.x & 63;
  long r = (long)blockIdx.x * 4 + w;
  const bf16* xp = x1 + r * DD;
  const float* fp = F + r * DD;
  float v[12], sum = 0.f, ssum = 0.f;
#pragma unroll
  for (int j = 0; j < 12; ++j) {
    int d = j * 64 + lane;
    float x = (float)xp[d] + fp[d];
    v[j] = x;
    sum += x;
    ssum += x * x;
  }
  sum = wred(sum);
  ssum = wred(ssum);
  float mean = sum * (1.0f / DD);
  float var = ssum * (1.0f / DD) - mean * mean;
  float rs = rsqrtf(var + 1e-12f);
  float acc = 0.f;
#pragma unroll
  for (int j = 0; j < 12; ++j) {
    int d = j * 64 + lane;
    float y = (v[j] - mean) * rs * g[d] + bb[d];
    acc += y * hw[d];
  }
  acc = wred(acc);
  if (lane == 0) scores[r] = acc + phb[0];
}

// ---------- launch ----------

extern "C" void kernel_launch(void* const* d_in, const int* in_sizes, int n_in,
                              void* d_out, int out_size, void* d_ws, size_t ws_size,
                              hipStream_t stream) {
  const int* hid = (const int*)d_in[0];
  const int* eid = (const int*)d_in[1];
  const int* tid = (const int*)d_in[2];
  const int* pL = (const int*)d_in[3];
  const float* tok = (const float*)d_in[4];
  const float* rel = (const float*)d_in[5];
  const float* ete = (const float*)d_in[6];
  const float* cls = (const float*)d_in[7];
  const float* seg = (const float*)d_in[8];
  const float* pos = (const float*)d_in[9];
  const float* lng = (const float*)d_in[10];
  const float* lnb = (const float*)d_in[11];
  const float* Wq = (const float*)d_in[12];
  const float* bq = (const float*)d_in[13];
  const float* Wk = (const float*)d_in[14];
  const float* bk = (const float*)d_in[15];
  const float* Wv = (const float*)d_in[16];
  const float* bv = (const float*)d_in[17];
  const float* Wo = (const float*)d_in[18];
  const float* bo = (const float*)d_in[19];
  const float* l1g = (const float*)d_in[20];
  const float* l1b = (const float*)d_in[21];
  const float* W1 = (const float*)d_in[22];
  const float* b1 = (const float*)d_in[23];
  const float* W2 = (const float*)d_in[24];
  const float* b2 = (const float*)d_in[25];
  const float* l2g = (const float*)d_in[26];
  const float* l2b = (const float*)d_in[27];
  const float* hw = (const float*)d_in[28];
  const float* phb = (const float*)d_in[29];
  float* scores = (float*)d_out;

  char* base = (char*)d_ws;
  size_t off = 0;
  auto alloc = [&](size_t bytes) -> char* {
    char* p = base + off;
    off += (bytes + 255) & ~(size_t)255;
    return p;
  };

  // ---- persistent buffers (~64.5 MB) ----
  bf16* Xc = (bf16*)alloc((size_t)NB * DD * 2);   // cls rows of LN'd embeddings
  bf16* ctx = (bf16*)alloc((size_t)NB * DD * 2);  // attention output (cls)
  bf16* WkvT = (bf16*)alloc((size_t)2 * DD * DD * 2);
  bf16* WqT = (bf16*)alloc((size_t)DD * DD * 2);
  bf16* WoT = (bf16*)alloc((size_t)DD * DD * 2);
  bf16* W1T = (bf16*)alloc((size_t)DD * FFD * 2);
  bf16* W2T = (bf16*)alloc((size_t)FFD * DD * 2);
  float* bkv = (float*)alloc((size_t)2 * DD * 4);

  // ---- chunk config from remaining workspace ----
  // phase1 bytes per triple: X(4*768*2) + KV(8*768*2) + Q(768*2) = 19968
  // phase2 bytes per row:    O(768*4) + x1(768*2) + Hff(3072*2)  = 10752
  size_t avail = (ws_size > off) ? (ws_size - off) : 0;
  auto need = [](long ra, long rb) -> size_t {
    size_t p1 = (size_t)ra * 19968, p2 = (size_t)rb * 10752;
    return ((p1 > p2 ? p1 : p2) + (size_t)(1 << 20));
  };
  int CHA, CHB;
  if (avail >= need(16384, 16384)) {
    CHA = 1; CHB = 1;
  } else if (avail >= need(4096, 8192)) {
    CHA = 4; CHB = 2;
  } else if (avail >= need(1024, 2048)) {
    CHA = 16; CHB = 8;
  } else {
    CHA = 64; CHB = 32;  // ~70 MB total requirement
  }
  const long RA = NB / CHA;  // triples per attention chunk
  const long RB = NB / CHB;  // cls rows per tail chunk

  char* region = base + off;
  // phase-1 scratch layout
  bf16* Xch = (bf16*)region;
  bf16* KVch = Xch + RA * 4 * DD;
  bf16* Qch = KVch + RA * 4 * 2 * DD;
  // phase-2 scratch layout (same region, phase-1 dead by then)
  float* Och = (float*)region;
  bf16* x1ch = (bf16*)(region + (size_t)RB * DD * 4);
  bf16* Hffch = x1ch + RB * DD;
  float* Foch = Och;  // O dead after ln1

  // ---- weight prep (bf16 transpose) ----
  transpose_bf16<<<576, 256, 0, stream>>>(Wk, WkvT, DD, DD);
  transpose_bf16<<<576, 256, 0, stream>>>(Wv, WkvT + (size_t)DD * DD, DD, DD);
  transpose_bf16<<<576, 256, 0, stream>>>(Wq, WqT, DD, DD);
  transpose_bf16<<<576, 256, 0, stream>>>(Wo, WoT, DD, DD);
  transpose_bf16<<<2304, 256, 0, stream>>>(W1, W1T, DD, FFD);
  transpose_bf16<<<2304, 256, 0, stream>>>(W2, W2T, FFD, DD);
  concat_bias<<<6, 256, 0, stream>>>(bk, bv, bkv);

  // ---- phase 1: embeddings, K/V, Q, attention (chunked over triples) ----
  for (int c = 0; c < CHA; ++c) {
    long b0 = (long)c * RA;
    embed_kernel<<<RA, 256, 0, stream>>>(b0, hid, eid, tid, pL, tok, rel, ete, cls, seg,
                                         pos, lng, lnb, Xch, Xc);
    gemm_bt<0><<<(RA * 4 / 128) * 12, 256, 0, stream>>>(Xch, WkvT, bkv, KVch,
                                                        RA * 4, 2 * DD, DD, 12);
    gemm_bt<0><<<(RA / 128) * 6, 256, 0, stream>>>(Xc + b0 * DD, WqT, bq, Qch,
                                                   RA, DD, DD, 6);
    attn_kernel<<<RA, 192, 0, stream>>>(Qch, KVch, ctx, b0);
  }

  // ---- phase 2: Wo-proj, LN1, FFN, LN2+score (chunked over cls rows) ----
  for (int j = 0; j < CHB; ++j) {
    long r0 = (long)j * RB;
    gemm_bt<1><<<(RB / 128) * 6, 256, 0, stream>>>(ctx + r0 * DD, WoT, bo, Och,
                                                   RB, DD, DD, 6);
    ln1_kernel<<<RB / 4, 256, 0, stream>>>(Xc + r0 * DD, Och, l1g, l1b, x1ch);
    gemm_bt<2><<<(RB / 128) * 24, 256, 0, stream>>>(x1ch, W1T, b1, Hffch,
                                                    RB, FFD, DD, 24);
    gemm_bt<1><<<(RB / 128) * 6, 256, 0, stream>>>(Hffch, W2T, b2, Foch,
                                                   RB, DD, FFD, 6);
    final_kernel<<<RB / 4, 256, 0, stream>>>(x1ch, Foch, l2g, l2b, hw, phb, scores + r0);
  }
}

// Round 4
// 600.540 us; speedup vs baseline: 1.5558x; 1.5558x over previous
//
#include <hip/hip_runtime.h>

typedef __bf16 bf16;
typedef __bf16 bf16x8 __attribute__((ext_vector_type(8)));
typedef float f32x4 __attribute__((ext_vector_type(4)));

constexpr long NB = 16384;   // batch of triples
constexpr int  DD = 768;
constexpr int  FFD = 3072;
constexpr int  NH = 12;

// ---------- helpers ----------

__device__ __forceinline__ void async16(const void* g, void* l) {
  void* gg = (void*)g;
  __builtin_amdgcn_global_load_lds((__attribute__((address_space(1))) void*)gg,
                                   (__attribute__((address_space(3))) void*)l,
                                   16, 0, 0);
}

__device__ __forceinline__ float wred(float v) {
#pragma unroll
  for (int off = 32; off; off >>= 1) v += __shfl_xor(v, off);
  return v;
}

__device__ __forceinline__ float gelu_tanh(float x) {
  float x3 = x * x * x;
  return 0.5f * x * (1.0f + tanhf(0.7978845608028654f * (x + 0.044715f * x3)));
}

// ---------- weight prep: fp32 [R][C] -> bf16 [C][R] (transpose) ----------

__global__ __launch_bounds__(256) void transpose_bf16(const float* __restrict__ src,
                                                      bf16* __restrict__ dst,
                                                      int R, int C) {
  __shared__ float t[32][33];
  int tilesC = C >> 5;
  int tc = blockIdx.x % tilesC;
  int tr = blockIdx.x / tilesC;
  int tx = threadIdx.x & 31, ty = threadIdx.x >> 5;  // ty in 0..7
#pragma unroll
  for (int i = 0; i < 4; ++i) {
    int r = tr * 32 + ty + i * 8;
    t[ty + i * 8][tx] = src[(long)r * C + tc * 32 + tx];
  }
  __syncthreads();
#pragma unroll
  for (int i = 0; i < 4; ++i) {
    int c = tc * 32 + ty + i * 8;
    dst[(long)c * R + tr * 32 + tx] = (bf16)t[tx][ty + i * 8];
  }
}

__global__ void concat_bias(const float* __restrict__ bk, const float* __restrict__ bv,
                            float* __restrict__ bkv) {
  int i = blockIdx.x * 256 + threadIdx.x;
  if (i < 2 * DD) bkv[i] = (i < DD) ? bk[i] : bv[i - DD];
}

// ---------- vocabulary-table embedding + LN ----------
// table rows: [0,VOC) node id at HEAD position (s=1); [VOC,2VOC) node id at TAIL
// position (s=3); [2VOC,2VOC+NE) edge types (s=2); [2VOC+NE] the cls row (s=0).
// 4 rows per block, one wave per row.

__global__ __launch_bounds__(256) void embed_table_kernel(
    const int* __restrict__ pL,
    const float* __restrict__ tok, const float* __restrict__ rel, const float* __restrict__ ete,
    const float* __restrict__ cls, const float* __restrict__ seg, const float* __restrict__ pos,
    const float* __restrict__ g, const float* __restrict__ bln,
    bf16* __restrict__ Xtab, int VOC, int NE, int Mtab, int nrel) {
  long row = (long)blockIdx.x * 4 + (threadIdx.x >> 6);
  int lane = threadIdx.x & 63;
  if (row >= Mtab) return;
  int L = *pL;

  const float* src;
  int s;
  if (row < VOC || row < 2 * VOC) {
    if (row < VOC) { s = 1; } else { s = 3; }
    int id = (int)(row < VOC ? row : row - VOC);
    if (row >= 2 * VOC) { /* unreachable */ }
    if (id < L) {
      src = tok + (long)id * DD;
    } else {
      int ridx = id - L;
      ridx = ridx < 0 ? 0 : (ridx > nrel - 1 ? nrel - 1 : ridx);
      src = rel + (long)ridx * DD;
    }
    if (row >= 2 * VOC) src = cls;  // safety, not reached
  } else if (row < 2 * VOC + NE) {
    s = 2;
    src = ete + (row - 2 * (long)VOC) * DD;
  } else {
    s = 0;
    src = cls;
  }
  // fix the branch mess above for edge/cls (rows >= 2*VOC fall to else branches)
  if (row >= 2 * VOC) {
    if (row < 2 * VOC + NE) { s = 2; src = ete + (row - 2 * (long)VOC) * DD; }
    else { s = 0; src = cls; }
  }

  float v[12];
  float sum = 0.f, ssum = 0.f;
#pragma unroll
  for (int j = 0; j < 12; ++j) {
    int d = j * 64 + lane;
    float x = src[d] + seg[s * DD + d] + pos[s * DD + d];
    v[j] = x;
    sum += x;
    ssum += x * x;
  }
  sum = wred(sum);
  ssum = wred(ssum);
  float mean = sum * (1.0f / DD);
  float var = ssum * (1.0f / DD) - mean * mean;
  float rs = rsqrtf(var + 1e-12f);

#pragma unroll
  for (int j = 0; j < 12; ++j) {
    int d = j * 64 + lane;
    Xtab[row * DD + d] = (bf16)((v[j] - mean) * rs * g[d] + bln[d]);
  }
}

// ---------- GEMM: C = A(bf16,row-major MxK) @ Bt(bf16, [N][K]) + bias ----------
// m97 structure: 128x128 tile, BK=32, 4 waves (2x2), 16x16x32 bf16 MFMA.
// EPI: 0 = bf16 out, 1 = f32 out, 2 = bf16 out with gelu

template <int EPI>
__global__ __launch_bounds__(256) void gemm_bt(
    const bf16* __restrict__ A, const bf16* __restrict__ Bt,
    const float* __restrict__ bias, void* __restrict__ Cout,
    long M, long N, long K, int tilesN) {
  __shared__ __align__(16) bf16 As[128 * 32];
  __shared__ __align__(16) bf16 Bs[128 * 32];
  const int tid = threadIdx.x;
  const int w = tid >> 6;
  const int lane = tid & 63;

  long bid;
  if ((gridDim.x & 7) == 0) {
    const long cpx = gridDim.x >> 3;
    bid = (long)(blockIdx.x & 7) * cpx + (blockIdx.x >> 3);
  } else {
    bid = blockIdx.x;
  }
  const int tn = (int)(bid % tilesN);
  const long tm = bid / tilesN;
  const long m0 = tm * 128, n0 = (long)tn * 128;

  const int sr = lane >> 2;
  const int sk = (lane & 3) * 8;
  const bf16* ga0 = A + (m0 + w * 32 + sr) * K + sk;
  const bf16* ga1 = ga0 + 16 * K;
  const bf16* gb0 = Bt + (n0 + w * 32 + sr) * K + sk;
  const bf16* gb1 = gb0 + 16 * K;
  bf16* la0 = As + w * 1024;
  bf16* la1 = la0 + 512;
  bf16* lb0 = Bs + w * 1024;
  bf16* lb1 = lb0 + 512;

  const int fr = lane & 15;
  const int fk = (lane >> 4) * 8;
  const int wr = (w >> 1) * 64;
  const int wc = (w & 1) * 64;

  f32x4 acc[4][4] = {};

  const int nk = (int)(K >> 5);
  for (int kt = 0; kt < nk; ++kt) {
    const long ko = (long)kt * 32;
    async16(ga0 + ko, la0);
    async16(ga1 + ko, la1);
    async16(gb0 + ko, lb0);
    async16(gb1 + ko, lb1);
    __syncthreads();
    bf16x8 af[4], bfr[4];
#pragma unroll
    for (int m = 0; m < 4; ++m)
      af[m] = *(const bf16x8*)(As + (wr + m * 16 + fr) * 32 + fk);
#pragma unroll
    for (int n = 0; n < 4; ++n)
      bfr[n] = *(const bf16x8*)(Bs + (wc + n * 16 + fr) * 32 + fk);
#pragma unroll
    for (int m = 0; m < 4; ++m)
#pragma unroll
      for (int n = 0; n < 4; ++n)
        acc[m][n] = __builtin_amdgcn_mfma_f32_16x16x32_bf16(af[m], bfr[n], acc[m][n], 0, 0, 0);
    __syncthreads();
  }

  const int er = (lane >> 4) * 4;
#pragma unroll
  for (int m = 0; m < 4; ++m) {
#pragma unroll
    for (int n = 0; n < 4; ++n) {
#pragma unroll
      for (int j = 0; j < 4; ++j) {
        long row = m0 + wr + m * 16 + er + j;
        long col = n0 + wc + n * 16 + fr;
        float v = acc[m][n][j] + bias[col];
        if (EPI == 2) v = gelu_tanh(v);
        if (EPI == 1)
          ((float*)Cout)[row * N + col] = v;
        else
          ((bf16*)Cout)[row * N + col] = (bf16)v;
      }
    }
  }
}

// ---------- per-table-row attention scores: stab[row][h] = q . K_row[h] / 8 ----------
// 192 threads = 12 heads x 16 lanes, 4 dims/lane; one row per block.

__global__ __launch_bounds__(192) void score_kernel(const bf16* __restrict__ KVtab,
                                                    const float* __restrict__ q,
                                                    float* __restrict__ stab, int Mtab) {
  long row = blockIdx.x;
  int t = threadIdx.x, h = t >> 4, hl = t & 15;
  const bf16* kp = KVtab + row * (2 * DD) + h * 64 + hl * 4;
  const float* qp = q + h * 64 + hl * 4;
  float p = qp[0] * (float)kp[0] + qp[1] * (float)kp[1] + qp[2] * (float)kp[2] +
            qp[3] * (float)kp[3];
  p += __shfl_xor(p, 1);
  p += __shfl_xor(p, 2);
  p += __shfl_xor(p, 4);
  p += __shfl_xor(p, 8);
  if (hl == 0) stab[row * NH + h] = p * 0.125f;
}

// ---------- attention: gather 4 scores + 4 V rows per head, softmax, blend ----------

__global__ __launch_bounds__(192) void attn_kernel(
    const int* __restrict__ hid, const int* __restrict__ eid, const int* __restrict__ tid_,
    const bf16* __restrict__ KVtab, const float* __restrict__ stab,
    bf16* __restrict__ ctx, int VOC, int crow) {
  long b = blockIdx.x;
  int t = threadIdx.x, h = t >> 4, hl = t & 15;
  long r0 = crow;
  long r1 = hid[b];
  long r2 = 2L * VOC + eid[b];
  long r3 = (long)VOC + tid_[b];
  float s0 = stab[r0 * NH + h], s1 = stab[r1 * NH + h];
  float s2 = stab[r2 * NH + h], s3 = stab[r3 * NH + h];
  float m = fmaxf(fmaxf(s0, s1), fmaxf(s2, s3));
  float p0 = expf(s0 - m), p1 = expf(s1 - m), p2 = expf(s2 - m), p3 = expf(s3 - m);
  float inv = 1.0f / (p0 + p1 + p2 + p3);
  p0 *= inv; p1 *= inv; p2 *= inv; p3 *= inv;

  int o = h * 64 + hl * 4;
  const bf16* v0 = KVtab + r0 * (2 * DD) + DD + o;
  const bf16* v1 = KVtab + r1 * (2 * DD) + DD + o;
  const bf16* v2 = KVtab + r2 * (2 * DD) + DD + o;
  const bf16* v3 = KVtab + r3 * (2 * DD) + DD + o;
  bf16* op = ctx + b * DD + o;
#pragma unroll
  for (int j = 0; j < 4; ++j) {
    float v = p0 * (float)v0[j] + p1 * (float)v1[j] + p2 * (float)v2[j] + p3 * (float)v3[j];
    op[j] = (bf16)v;
  }
}

// ---------- LN1: x1 = LN(xrow_const + O) ----------

__global__ __launch_bounds__(256) void ln1_kernel(const bf16* __restrict__ xrow,
                                                  const float* __restrict__ O,
                                                  const float* __restrict__ g,
                                                  const float* __restrict__ bb,
                                                  bf16* __restrict__ x1) {
  int w = threadIdx.x >> 6, lane = threadIdx.x & 63;
  long r = (long)blockIdx.x * 4 + w;
  const float* op = O + r * DD;
  float v[12], sum = 0.f, ssum = 0.f;
#pragma unroll
  for (int j = 0; j < 12; ++j) {
    int d = j * 64 + lane;
    float x = (float)xrow[d] + op[d];
    v[j] = x;
    sum += x;
    ssum += x * x;
  }
  sum = wred(sum);
  ssum = wred(ssum);
  float mean = sum * (1.0f / DD);
  float var = ssum * (1.0f / DD) - mean * mean;
  float rs = rsqrtf(var + 1e-12f);
#pragma unroll
  for (int j = 0; j < 12; ++j) {
    int d = j * 64 + lane;
    x1[r * DD + d] = (bf16)((v[j] - mean) * rs * g[d] + bb[d]);
  }
}

// ---------- LN2 + score ----------

__global__ __launch_bounds__(256) void final_kernel(const bf16* __restrict__ x1,
                                                    const float* __restrict__ F,
                                                    const float* __restrict__ g,
                                                    const float* __restrict__ bb,
                                                    const float* __restrict__ hw,
                                                    const float* __restrict__ phb,
                                                    float* __restrict__ scores) {
  int w = threadIdx.x >> 6, lane = threadIdx.x & 63;
  long r = (long)blockIdx.x * 4 + w;
  const bf16* xp = x1 + r * DD;
  const float* fp = F + r * DD;
  float v[12], sum = 0.f, ssum = 0.f;
#pragma unroll
  for (int j = 0; j < 12; ++j) {
    int d = j * 64 + lane;
    float x = (float)xp[d] + fp[d];
    v[j] = x;
    sum += x;
    ssum += x * x;
  }
  sum = wred(sum);
  ssum = wred(ssum);
  float mean = sum * (1.0f / DD);
  float var = ssum * (1.0f / DD) - mean * mean;
  float rs = rsqrtf(var + 1e-12f);
  float acc = 0.f;
#pragma unroll
  for (int j = 0; j < 12; ++j) {
    int d = j * 64 + lane;
    float y = (v[j] - mean) * rs * g[d] + bb[d];
    acc += y * hw[d];
  }
  acc = wred(acc);
  if (lane == 0) scores[r] = acc + phb[0];
}

// ---------- launch ----------

extern "C" void kernel_launch(void* const* d_in, const int* in_sizes, int n_in,
                              void* d_out, int out_size, void* d_ws, size_t ws_size,
                              hipStream_t stream) {
  const int* hid = (const int*)d_in[0];
  const int* eid = (const int*)d_in[1];
  const int* tid = (const int*)d_in[2];
  const int* pL = (const int*)d_in[3];
  const float* tok = (const float*)d_in[4];
  const float* rel = (const float*)d_in[5];
  const float* ete = (const float*)d_in[6];
  const float* cls = (const float*)d_in[7];
  const float* seg = (const float*)d_in[8];
  const float* pos = (const float*)d_in[9];
  const float* lng = (const float*)d_in[10];
  const float* lnb = (const float*)d_in[11];
  const float* Wq = (const float*)d_in[12];
  const float* bq = (const float*)d_in[13];
  const float* Wk = (const float*)d_in[14];
  const float* bk = (const float*)d_in[15];
  const float* Wv = (const float*)d_in[16];
  const float* bv = (const float*)d_in[17];
  const float* Wo = (const float*)d_in[18];
  const float* bo = (const float*)d_in[19];
  const float* l1g = (const float*)d_in[20];
  const float* l1b = (const float*)d_in[21];
  const float* W1 = (const float*)d_in[22];
  const float* b1 = (const float*)d_in[23];
  const float* W2 = (const float*)d_in[24];
  const float* b2 = (const float*)d_in[25];
  const float* l2g = (const float*)d_in[26];
  const float* l2b = (const float*)d_in[27];
  const float* hw = (const float*)d_in[28];
  const float* phb = (const float*)d_in[29];
  float* scores = (float*)d_out;

  const int VOC = in_sizes[4] / DD;    // 8704
  const int NE = in_sizes[6] / DD;     // 64
  const int NREL = in_sizes[5] / DD;   // 512
  const int Mtab = 2 * VOC + NE + 1;   // 17473
  const int Mpad = (Mtab + 127) & ~127;  // 17536
  const int crow = 2 * VOC + NE;       // cls row index

  char* base = (char*)d_ws;
  size_t off = 0;
  auto alloc = [&](size_t bytes) -> char* {
    char* p = base + off;
    off += (bytes + 255) & ~(size_t)255;
    return p;
  };

  // ---- persistent buffers (~67 MB) ----
  bf16* WkvT = (bf16*)alloc((size_t)2 * DD * DD * 2);
  bf16* WqT = (bf16*)alloc((size_t)DD * DD * 2);
  bf16* WoT = (bf16*)alloc((size_t)DD * DD * 2);
  bf16* W1T = (bf16*)alloc((size_t)DD * FFD * 2);
  bf16* W2T = (bf16*)alloc((size_t)FFD * DD * 2);
  float* bkv = (float*)alloc((size_t)2 * DD * 4);
  bf16* Xtab = (bf16*)alloc((size_t)Mpad * DD * 2);          // 26.9 MB
  float* stab = (float*)alloc((size_t)Mtab * NH * 4);        // 0.85 MB
  float* Q128 = (float*)alloc((size_t)128 * DD * 4);         // 0.4 MB
  bf16* ctx = (bf16*)alloc((size_t)NB * DD * 2);             // 25.2 MB

  // ---- transient region: KVtab during phase 1, GEMM scratch during phase 2 ----
  char* region = base + off;
  size_t region_sz = (ws_size > off) ? (ws_size - off) : 0;
  bf16* KVtab = (bf16*)region;  // Mpad x 1536 bf16 = 53.9 MB

  // phase-2 chunk size (rows per chunk), needs 10752 B/row in region
  long RB = NB;
  while (RB > 512 && (size_t)RB * 10752 + (1 << 20) > region_sz) RB >>= 1;
  const int CHB = (int)(NB / RB);
  float* Och = (float*)region;
  bf16* x1ch = (bf16*)(region + (size_t)RB * DD * 4);
  bf16* Hffch = x1ch + RB * DD;
  float* Foch = Och;  // O dead after ln1

  // ---- weight prep ----
  transpose_bf16<<<576, 256, 0, stream>>>(Wk, WkvT, DD, DD);
  transpose_bf16<<<576, 256, 0, stream>>>(Wv, WkvT + (size_t)DD * DD, DD, DD);
  transpose_bf16<<<576, 256, 0, stream>>>(Wq, WqT, DD, DD);
  transpose_bf16<<<576, 256, 0, stream>>>(Wo, WoT, DD, DD);
  transpose_bf16<<<2304, 256, 0, stream>>>(W1, W1T, DD, FFD);
  transpose_bf16<<<2304, 256, 0, stream>>>(W2, W2T, FFD, DD);
  concat_bias<<<6, 256, 0, stream>>>(bk, bv, bkv);

  // ---- vocabulary table ----
  embed_table_kernel<<<(Mtab + 3) / 4, 256, 0, stream>>>(
      pL, tok, rel, ete, cls, seg, pos, lng, lnb, Xtab, VOC, NE, Mtab, NREL);

  // KV for all table rows
  gemm_bt<0><<<(Mpad / 128) * 12, 256, 0, stream>>>(Xtab, WkvT, bkv, KVtab,
                                                    Mpad, 2 * DD, DD, 12);
  // q for the cls row: run a 128-row GEMM over the table tail (crow lands at local row 64)
  gemm_bt<1><<<6, 256, 0, stream>>>(Xtab + (size_t)(Mpad - 128) * DD, WqT, bq, Q128,
                                    128, DD, DD, 6);
  // per-row, per-head scores
  score_kernel<<<Mtab, 192, 0, stream>>>(KVtab, Q128 + (size_t)(crow - (Mpad - 128)) * DD,
                                         stab, Mtab);
  // attention gather
  attn_kernel<<<NB, 192, 0, stream>>>(hid, eid, tid, KVtab, stab, ctx, VOC, crow);

  // ---- phase 2: Wo-proj, LN1, FFN, LN2+score (chunked over cls rows) ----
  const bf16* xrow = Xtab + (size_t)crow * DD;
  for (int j = 0; j < CHB; ++j) {
    long r0 = (long)j * RB;
    gemm_bt<1><<<(RB / 128) * 6, 256, 0, stream>>>(ctx + r0 * DD, WoT, bo, Och,
                                                   RB, DD, DD, 6);
    ln1_kernel<<<RB / 4, 256, 0, stream>>>(xrow, Och, l1g, l1b, x1ch);
    gemm_bt<2><<<(RB / 128) * 24, 256, 0, stream>>>(x1ch, W1T, b1, Hffch,
                                                    RB, FFD, DD, 24);
    gemm_bt<1><<<(RB / 128) * 6, 256, 0, stream>>>(Hffch, W2T, b2, Foch,
                                                   RB, DD, FFD, 6);
    final_kernel<<<RB / 4, 256, 0, stream>>>(x1ch, Foch, l2g, l2b, hw, phb, scores + r0);
  }
}

// Round 11
// 528.835 us; speedup vs baseline: 1.7668x; 1.1356x over previous
//
#include <hip/hip_runtime.h>

typedef __bf16 bf16;
typedef __bf16 bf16x8 __attribute__((ext_vector_type(8)));
typedef float f32x4 __attribute__((ext_vector_type(4)));

constexpr long NB = 16384;   // batch of triples
constexpr int  DD = 768;
constexpr int  FFD = 3072;
constexpr int  NH = 12;

// ---------- helpers ----------

__device__ __forceinline__ void async16(const void* g, void* l) {
  void* gg = (void*)g;
  __builtin_amdgcn_global_load_lds((__attribute__((address_space(1))) void*)gg,
                                   (__attribute__((address_space(3))) void*)l,
                                   16, 0, 0);
}

__device__ __forceinline__ float wred(float v) {
#pragma unroll
  for (int off = 32; off; off >>= 1) v += __shfl_xor(v, off);
  return v;
}

// gelu tanh-approx via e^{2z}: tanh(z)=(t-1)/(t+1), gelu = x*t/(t+1)
__device__ __forceinline__ float gelu_fast(float x) {
  float z = 1.5957691216f * (x + 0.044715f * x * x * x);  // 2*0.79788456*inner
  z = fminf(fmaxf(z, -30.f), 30.f);
  float t = __expf(z);
  return x * t / (t + 1.f);
}

// ---------- weight prep: fp32 [R][C] -> bf16 [C][R] (transpose) ----------

__global__ __launch_bounds__(256) void transpose_bf16(const float* __restrict__ src,
                                                      bf16* __restrict__ dst,
                                                      int R, int C) {
  __shared__ float t[32][33];
  int tilesC = C >> 5;
  int tc = blockIdx.x % tilesC;
  int tr = blockIdx.x / tilesC;
  int tx = threadIdx.x & 31, ty = threadIdx.x >> 5;
#pragma unroll
  for (int i = 0; i < 4; ++i) {
    int r = tr * 32 + ty + i * 8;
    t[ty + i * 8][tx] = src[(long)r * C + tc * 32 + tx];
  }
  __syncthreads();
#pragma unroll
  for (int i = 0; i < 4; ++i) {
    int c = tc * 32 + ty + i * 8;
    dst[(long)c * R + tr * 32 + tx] = (bf16)t[tx][ty + i * 8];
  }
}

__global__ void concat_bias(const float* __restrict__ bk, const float* __restrict__ bv,
                            float* __restrict__ bkv) {
  int i = blockIdx.x * 256 + threadIdx.x;
  if (i < 2 * DD) bkv[i] = (i < DD) ? bk[i] : bv[i - DD];
}

// ---------- vocabulary-table embedding + LN ----------
// rows: [0,VOC) node@HEAD(s=1); [VOC,2VOC) node@TAIL(s=3); [2VOC,2VOC+NE) edge(s=2);
// [2VOC+NE] cls(s=0). 4 rows/block, one wave per row.

__global__ __launch_bounds__(256) void embed_table_kernel(
    const int* __restrict__ pL,
    const float* __restrict__ tok, const float* __restrict__ rel, const float* __restrict__ ete,
    const float* __restrict__ cls, const float* __restrict__ seg, const float* __restrict__ pos,
    const float* __restrict__ g, const float* __restrict__ bln,
    bf16* __restrict__ Xtab, int VOC, int NE, int Mtab, int nrel) {
  long row = (long)blockIdx.x * 4 + (threadIdx.x >> 6);
  int lane = threadIdx.x & 63;
  if (row >= Mtab) return;
  int L = *pL;

  const float* src;
  int s;
  if (row < 2 * VOC) {
    s = (row < VOC) ? 1 : 3;
    int id = (int)(row < VOC ? row : row - VOC);
    if (id < L) {
      src = tok + (long)id * DD;
    } else {
      int ridx = id - L;
      ridx = ridx < 0 ? 0 : (ridx > nrel - 1 ? nrel - 1 : ridx);
      src = rel + (long)ridx * DD;
    }
  } else if (row < 2 * VOC + NE) {
    s = 2;
    src = ete + (row - 2 * (long)VOC) * DD;
  } else {
    s = 0;
    src = cls;
  }

  float v[12];
  float sum = 0.f, ssum = 0.f;
#pragma unroll
  for (int j = 0; j < 12; ++j) {
    int d = j * 64 + lane;
    float x = src[d] + seg[s * DD + d] + pos[s * DD + d];
    v[j] = x;
    sum += x;
    ssum += x * x;
  }
  sum = wred(sum);
  ssum = wred(ssum);
  float mean = sum * (1.0f / DD);
  float var = ssum * (1.0f / DD) - mean * mean;
  float rs = rsqrtf(var + 1e-12f);

#pragma unroll
  for (int j = 0; j < 12; ++j) {
    int d = j * 64 + lane;
    Xtab[row * DD + d] = (bf16)((v[j] - mean) * rs * g[d] + bln[d]);
  }
}

// ---------- 256x256 2-phase pipelined GEMM ----------
// C = A(bf16 MxK) @ Bt(bf16 [N][K]) + bias. 512 threads = 8 waves (2M x 4N),
// BK=64, double-buffered 128 KiB LDS, stage(next) || compute(cur), 1 barrier/tile.
// EPI: 0 = bf16 out, 1 = f32 out, 2 = bf16 out + gelu. M%256==0, N%256==0, K%64==0.

template <int EPI>
__global__ __launch_bounds__(512) void gemm256(
    const bf16* __restrict__ A, const bf16* __restrict__ Bt,
    const float* __restrict__ bias, void* __restrict__ Cout,
    long M, long N, long K, int tilesN) {
  __shared__ __align__(16) bf16 lds[65536];  // A: [2][256][64] @0, B: @32768
  const int tid = threadIdx.x;
  const int w = tid >> 6;
  const int lane = tid & 63;
  const int wm = w >> 2;   // 0..1
  const int wn = w & 3;    // 0..3

  long bid;
  if ((gridDim.x & 7) == 0) {
    const long cpx = gridDim.x >> 3;
    bid = (long)(blockIdx.x & 7) * cpx + (blockIdx.x >> 3);
  } else {
    bid = blockIdx.x;
  }
  const int tn = (int)(bid % tilesN);
  const long tm = bid / tilesN;
  const long m0 = tm * 256, n0 = (long)tn * 256;

  // staging geometry: per chunk c (64 rows), all 512 threads cover 64x64 elems
  const int srow = tid >> 3;        // 0..63
  const int scol = (tid & 7) * 8;   // k element
  const bf16* gA = A + (m0 + srow) * K + scol;
  const bf16* gB = Bt + (n0 + srow) * K + scol;
  const int ldsw = w * 512;         // wave-uniform lds base offset (elems) in chunk

  // fragment coords
  const int fr = lane & 15;
  const int fk = (lane >> 4) * 8;

  f32x4 acc[8][4] = {};

  auto STAGE = [&](int d, long ko) {
    bf16* a = lds + d * 16384;
    bf16* bb = lds + 32768 + d * 16384;
#pragma unroll
    for (int c = 0; c < 4; ++c)
      async16(gA + (long)(c * 64) * K + ko, a + c * 4096 + ldsw);
#pragma unroll
    for (int c = 0; c < 4; ++c)
      async16(gB + (long)(c * 64) * K + ko, bb + c * 4096 + ldsw);
  };

  auto COMPUTE = [&](int d) {
    const bf16* a = lds + d * 16384 + (wm * 128 + fr) * 64 + fk;
    const bf16* bb = lds + 32768 + d * 16384 + (wn * 64 + fr) * 64 + fk;
#pragma unroll
    for (int ks = 0; ks < 2; ++ks) {
      bf16x8 af[8], bf_[4];
#pragma unroll
      for (int mf = 0; mf < 8; ++mf)
        af[mf] = *(const bf16x8*)(a + mf * 16 * 64 + ks * 32);
#pragma unroll
      for (int nf = 0; nf < 4; ++nf)
        bf_[nf] = *(const bf16x8*)(bb + nf * 16 * 64 + ks * 32);
#pragma unroll
      for (int mf = 0; mf < 8; ++mf)
#pragma unroll
        for (int nf = 0; nf < 4; ++nf)
          acc[mf][nf] =
              __builtin_amdgcn_mfma_f32_16x16x32_bf16(af[mf], bf_[nf], acc[mf][nf], 0, 0, 0);
    }
  };

  const int nt = (int)(K >> 6);
  STAGE(0, 0);
  __syncthreads();
  int cur = 0;
  for (int kt = 0; kt < nt - 1; ++kt) {
    STAGE(cur ^ 1, (long)(kt + 1) * 64);
    COMPUTE(cur);
    __syncthreads();
    cur ^= 1;
  }
  COMPUTE(cur);

  // epilogue: C/D layout col=lane&15, row=(lane>>4)*4+j
  const int er = (lane >> 4) * 4;
#pragma unroll
  for (int mf = 0; mf < 8; ++mf) {
#pragma unroll
    for (int nf = 0; nf < 4; ++nf) {
#pragma unroll
      for (int j = 0; j < 4; ++j) {
        long row = m0 + wm * 128 + mf * 16 + er + j;
        long col = n0 + wn * 64 + nf * 16 + fr;
        float v = acc[mf][nf][j] + bias[col];
        if (EPI == 2) v = gelu_fast(v);
        if (EPI == 1)
          ((float*)Cout)[row * N + col] = v;
        else
          ((bf16*)Cout)[row * N + col] = (bf16)v;
      }
    }
  }
}

// ---------- m97 128x128 GEMM (kept for the tiny Q projection) ----------

template <int EPI>
__global__ __launch_bounds__(256) void gemm_bt(
    const bf16* __restrict__ A, const bf16* __restrict__ Bt,
    const float* __restrict__ bias, void* __restrict__ Cout,
    long M, long N, long K, int tilesN) {
  __shared__ __align__(16) bf16 As[128 * 32];
  __shared__ __align__(16) bf16 Bs[128 * 32];
  const int tid = threadIdx.x;
  const int w = tid >> 6;
  const int lane = tid & 63;

  long bid = blockIdx.x;
  const int tn = (int)(bid % tilesN);
  const long tm = bid / tilesN;
  const long m0 = tm * 128, n0 = (long)tn * 128;

  const int sr = lane >> 2;
  const int sk = (lane & 3) * 8;
  const bf16* ga0 = A + (m0 + w * 32 + sr) * K + sk;
  const bf16* ga1 = ga0 + 16 * K;
  const bf16* gb0 = Bt + (n0 + w * 32 + sr) * K + sk;
  const bf16* gb1 = gb0 + 16 * K;
  bf16* la0 = As + w * 1024;
  bf16* la1 = la0 + 512;
  bf16* lb0 = Bs + w * 1024;
  bf16* lb1 = lb0 + 512;

  const int fr = lane & 15;
  const int fk = (lane >> 4) * 8;
  const int wr = (w >> 1) * 64;
  const int wc = (w & 1) * 64;

  f32x4 acc[4][4] = {};

  const int nk = (int)(K >> 5);
  for (int kt = 0; kt < nk; ++kt) {
    const long ko = (long)kt * 32;
    async16(ga0 + ko, la0);
    async16(ga1 + ko, la1);
    async16(gb0 + ko, lb0);
    async16(gb1 + ko, lb1);
    __syncthreads();
    bf16x8 af[4], bfr[4];
#pragma unroll
    for (int m = 0; m < 4; ++m)
      af[m] = *(const bf16x8*)(As + (wr + m * 16 + fr) * 32 + fk);
#pragma unroll
    for (int n = 0; n < 4; ++n)
      bfr[n] = *(const bf16x8*)(Bs + (wc + n * 16 + fr) * 32 + fk);
#pragma unroll
    for (int m = 0; m < 4; ++m)
#pragma unroll
      for (int n = 0; n < 4; ++n)
        acc[m][n] = __builtin_amdgcn_mfma_f32_16x16x32_bf16(af[m], bfr[n], acc[m][n], 0, 0, 0);
    __syncthreads();
  }

  const int er = (lane >> 4) * 4;
#pragma unroll
  for (int m = 0; m < 4; ++m) {
#pragma unroll
    for (int n = 0; n < 4; ++n) {
#pragma unroll
      for (int j = 0; j < 4; ++j) {
        long row = m0 + wr + m * 16 + er + j;
        long col = n0 + wc + n * 16 + fr;
        float v = acc[m][n][j] + bias[col];
        if (EPI == 1)
          ((float*)Cout)[row * N + col] = v;
        else
          ((bf16*)Cout)[row * N + col] = (bf16)v;
      }
    }
  }
}

// ---------- per-table-row attention scores: stab[row][h] = q . K_row[h] / 8 ----------

__global__ __launch_bounds__(192) void score_kernel(const bf16* __restrict__ KVtab,
                                                    const float* __restrict__ q,
                                                    float* __restrict__ stab, int Mtab) {
  long row = blockIdx.x;
  int t = threadIdx.x, h = t >> 4, hl = t & 15;
  const bf16* kp = KVtab + row * (2 * DD) + h * 64 + hl * 4;
  const float* qp = q + h * 64 + hl * 4;
  float p = qp[0] * (float)kp[0] + qp[1] * (float)kp[1] + qp[2] * (float)kp[2] +
            qp[3] * (float)kp[3];
  p += __shfl_xor(p, 1);
  p += __shfl_xor(p, 2);
  p += __shfl_xor(p, 4);
  p += __shfl_xor(p, 8);
  if (hl == 0) stab[row * NH + h] = p * 0.125f;
}

// ---------- attention: gather 4 scores + 4 V rows per head, softmax, blend ----------

__global__ __launch_bounds__(192) void attn_kernel(
    const int* __restrict__ hid, const int* __restrict__ eid, const int* __restrict__ tid_,
    const bf16* __restrict__ KVtab, const float* __restrict__ stab,
    bf16* __restrict__ ctx, int VOC, int crow) {
  long b = blockIdx.x;
  int t = threadIdx.x, h = t >> 4, hl = t & 15;
  long r0 = crow;
  long r1 = hid[b];
  long r2 = 2L * VOC + eid[b];
  long r3 = (long)VOC + tid_[b];
  float s0 = stab[r0 * NH + h], s1 = stab[r1 * NH + h];
  float s2 = stab[r2 * NH + h], s3 = stab[r3 * NH + h];
  float m = fmaxf(fmaxf(s0, s1), fmaxf(s2, s3));
  float p0 = expf(s0 - m), p1 = expf(s1 - m), p2 = expf(s2 - m), p3 = expf(s3 - m);
  float inv = 1.0f / (p0 + p1 + p2 + p3);
  p0 *= inv; p1 *= inv; p2 *= inv; p3 *= inv;

  int o = h * 64 + hl * 4;
  const bf16* v0 = KVtab + r0 * (2 * DD) + DD + o;
  const bf16* v1 = KVtab + r1 * (2 * DD) + DD + o;
  const bf16* v2 = KVtab + r2 * (2 * DD) + DD + o;
  const bf16* v3 = KVtab + r3 * (2 * DD) + DD + o;
  bf16* op = ctx + b * DD + o;
#pragma unroll
  for (int j = 0; j < 4; ++j) {
    float v = p0 * (float)v0[j] + p1 * (float)v1[j] + p2 * (float)v2[j] + p3 * (float)v3[j];
    op[j] = (bf16)v;
  }
}

// ---------- LN1: x1 = LN(xrow_const + O) ----------

__global__ __launch_bounds__(256) void ln1_kernel(const bf16* __restrict__ xrow,
                                                  const bf16* __restrict__ O,
                                                  const float* __restrict__ g,
                                                  const float* __restrict__ bb,
                                                  bf16* __restrict__ x1) {
  int w = threadIdx.x >> 6, lane = threadIdx.x & 63;
  long r = (long)blockIdx.x * 4 + w;
  const bf16* op = O + r * DD;
  float v[12], sum = 0.f, ssum = 0.f;
#pragma unroll
  for (int j = 0; j < 12; ++j) {
    int d = j * 64 + lane;
    float x = (float)xrow[d] + (float)op[d];
    v[j] = x;
    sum += x;
    ssum += x * x;
  }
  sum = wred(sum);
  ssum = wred(ssum);
  float mean = sum * (1.0f / DD);
  float var = ssum * (1.0f / DD) - mean * mean;
  float rs = rsqrtf(var + 1e-12f);
#pragma unroll
  for (int j = 0; j < 12; ++j) {
    int d = j * 64 + lane;
    x1[r * DD + d] = (bf16)((v[j] - mean) * rs * g[d] + bb[d]);
  }
}

// ---------- LN2 + score ----------

__global__ __launch_bounds__(256) void final_kernel(const bf16* __restrict__ x1,
                                                    const bf16* __restrict__ F,
                                                    const float* __restrict__ g,
                                                    const float* __restrict__ bb,
                                                    const float* __restrict__ hw,
                                                    const float* __restrict__ phb,
                                                    float* __restrict__ scores) {
  int w = threadIdx.x >> 6, lane = threadIdx.x & 63;
  long r = (long)blockIdx.x * 4 + w;
  const bf16* xp = x1 + r * DD;
  const bf16* fp = F + r * DD;
  float v[12], sum = 0.f, ssum = 0.f;
#pragma unroll
  for (int j = 0; j < 12; ++j) {
    int d = j * 64 + lane;
    float x = (float)xp[d] + (float)fp[d];
    v[j] = x;
    sum += x;
    ssum += x * x;
  }
  sum = wred(sum);
  ssum = wred(ssum);
  float mean = sum * (1.0f / DD);
  float var = ssum * (1.0f / DD) - mean * mean;
  float rs = rsqrtf(var + 1e-12f);
  float acc = 0.f;
#pragma unroll
  for (int j = 0; j < 12; ++j) {
    int d = j * 64 + lane;
    float y = (v[j] - mean) * rs * g[d] + bb[d];
    acc += y * hw[d];
  }
  acc = wred(acc);
  if (lane == 0) scores[r] = acc + phb[0];
}

// ---------- launch ----------

extern "C" void kernel_launch(void* const* d_in, const int* in_sizes, int n_in,
                              void* d_out, int out_size, void* d_ws, size_t ws_size,
                              hipStream_t stream) {
  const int* hid = (const int*)d_in[0];
  const int* eid = (const int*)d_in[1];
  const int* tid = (const int*)d_in[2];
  const int* pL = (const int*)d_in[3];
  const float* tok = (const float*)d_in[4];
  const float* rel = (const float*)d_in[5];
  const float* ete = (const float*)d_in[6];
  const float* cls = (const float*)d_in[7];
  const float* seg = (const float*)d_in[8];
  const float* pos = (const float*)d_in[9];
  const float* lng = (const float*)d_in[10];
  const float* lnb = (const float*)d_in[11];
  const float* Wq = (const float*)d_in[12];
  const float* bq = (const float*)d_in[13];
  const float* Wk = (const float*)d_in[14];
  const float* bk = (const float*)d_in[15];
  const float* Wv = (const float*)d_in[16];
  const float* bv = (const float*)d_in[17];
  const float* Wo = (const float*)d_in[18];
  const float* bo = (const float*)d_in[19];
  const float* l1g = (const float*)d_in[20];
  const float* l1b = (const float*)d_in[21];
  const float* W1 = (const float*)d_in[22];
  const float* b1 = (const float*)d_in[23];
  const float* W2 = (const float*)d_in[24];
  const float* b2 = (const float*)d_in[25];
  const float* l2g = (const float*)d_in[26];
  const float* l2b = (const float*)d_in[27];
  const float* hw = (const float*)d_in[28];
  const float* phb = (const float*)d_in[29];
  float* scores = (float*)d_out;

  const int VOC = in_sizes[4] / DD;      // 8704
  const int NE = in_sizes[6] / DD;       // 64
  const int NREL = in_sizes[5] / DD;     // 512
  const int Mtab = 2 * VOC + NE + 1;     // 17473
  const int Mpad = (Mtab + 255) & ~255;  // 17664 (256-aligned for gemm256)
  const int crow = 2 * VOC + NE;         // cls row index

  char* base = (char*)d_ws;
  size_t off = 0;
  auto alloc = [&](size_t bytes) -> char* {
    char* p = base + off;
    off += (bytes + 255) & ~(size_t)255;
    return p;
  };

  // ---- persistent buffers ----
  bf16* WkvT = (bf16*)alloc((size_t)2 * DD * DD * 2);
  bf16* WqT = (bf16*)alloc((size_t)DD * DD * 2);
  bf16* WoT = (bf16*)alloc((size_t)DD * DD * 2);
  bf16* W1T = (bf16*)alloc((size_t)DD * FFD * 2);
  bf16* W2T = (bf16*)alloc((size_t)FFD * DD * 2);
  float* bkv = (float*)alloc((size_t)2 * DD * 4);
  bf16* Xtab = (bf16*)alloc((size_t)Mpad * DD * 2);    // 27.1 MB
  float* stab = (float*)alloc((size_t)Mtab * NH * 4);  // 0.85 MB
  float* Q128 = (float*)alloc((size_t)128 * DD * 4);
  bf16* ctx = (bf16*)alloc((size_t)NB * DD * 2);       // 25.2 MB

  // ---- transient region: KVtab (phase 1) / GEMM scratch (phase 2) ----
  char* region = base + off;
  size_t region_sz = (ws_size > off) ? (ws_size - off) : 0;
  bf16* KVtab = (bf16*)region;  // Mpad x 1536 bf16 = 54.3 MB

  // phase-2 chunk: O(bf16)+x1(bf16)+Hff(bf16) = 1536+1536+6144 = 9216 B/row
  long RB = NB;
  while (RB > 2048 && (size_t)RB * 9216 + (1 << 20) > region_sz) RB >>= 1;
  const int CHB = (int)(NB / RB);
  bf16* Och = (bf16*)region;
  bf16* x1ch = Och + RB * DD;
  bf16* Hffch = x1ch + RB * DD;
  bf16* Foch = Och;  // O dead after ln1

  // ---- weight prep ----
  transpose_bf16<<<576, 256, 0, stream>>>(Wk, WkvT, DD, DD);
  transpose_bf16<<<576, 256, 0, stream>>>(Wv, WkvT + (size_t)DD * DD, DD, DD);
  transpose_bf16<<<576, 256, 0, stream>>>(Wq, WqT, DD, DD);
  transpose_bf16<<<576, 256, 0, stream>>>(Wo, WoT, DD, DD);
  transpose_bf16<<<2304, 256, 0, stream>>>(W1, W1T, DD, FFD);
  transpose_bf16<<<2304, 256, 0, stream>>>(W2, W2T, FFD, DD);
  concat_bias<<<6, 256, 0, stream>>>(bk, bv, bkv);

  // ---- vocabulary table ----
  embed_table_kernel<<<(Mtab + 3) / 4, 256, 0, stream>>>(
      pL, tok, rel, ete, cls, seg, pos, lng, lnb, Xtab, VOC, NE, Mtab, NREL);

  // KV for all table rows (256-tile 2-phase GEMM)
  gemm256<0><<<(Mpad / 256) * 6, 512, 0, stream>>>(Xtab, WkvT, bkv, KVtab,
                                                   Mpad, 2 * DD, DD, 6);
  // q for the cls row (tiny 128-tile GEMM over the table tail; crow -> local row 64)
  gemm_bt<1><<<6, 256, 0, stream>>>(Xtab + (size_t)17408 * DD, WqT, bq, Q128,
                                    128, DD, DD, 6);
  score_kernel<<<Mtab, 192, 0, stream>>>(KVtab, Q128 + (size_t)(crow - 17408) * DD,
                                         stab, Mtab);
  attn_kernel<<<NB, 192, 0, stream>>>(hid, eid, tid, KVtab, stab, ctx, VOC, crow);

  // ---- phase 2: Wo-proj, LN1, FFN, LN2+score ----
  const bf16* xrow = Xtab + (size_t)crow * DD;
  for (int j = 0; j < CHB; ++j) {
    long r0 = (long)j * RB;
    gemm256<0><<<(RB / 256) * 3, 512, 0, stream>>>(ctx + r0 * DD, WoT, bo, Och,
                                                   RB, DD, DD, 3);
    ln1_kernel<<<RB / 4, 256, 0, stream>>>(xrow, Och, l1g, l1b, x1ch);
    gemm256<2><<<(RB / 256) * 12, 512, 0, stream>>>(x1ch, W1T, b1, Hffch,
                                                    RB, FFD, DD, 12);
    gemm256<0><<<(RB / 256) * 3, 512, 0, stream>>>(Hffch, W2T, b2, Foch,
                                                   RB, DD, FFD, 3);
    final_kernel<<<RB / 4, 256, 0, stream>>>(x1ch, Foch, l2g, l2b, hw, phb, scores + r0);
  }
}